// Round 6
// baseline (802.960 us; speedup 1.0000x reference)
//
#include <hip/hip_runtime.h>
#include <cstdint>
#include <cstddef>

#define HD 128
#define NEG_SLOPE 0.2f
#define BN_EPS 1e-5f

typedef __bf16 bf16x8 __attribute__((ext_vector_type(8)));
typedef float  f32x4  __attribute__((ext_vector_type(4)));

__device__ __forceinline__ unsigned short f2b(float f) {   // fp32 -> bf16 RNE
    unsigned int u = __float_as_uint(f);
    u = (u + 0x7fffu + ((u >> 16) & 1u)) >> 16;
    return (unsigned short)u;
}
__device__ __forceinline__ unsigned int pack2(float lo, float hi) {
    return (unsigned int)f2b(lo) | ((unsigned int)f2b(hi) << 16);
}
__device__ __forceinline__ bf16x8 as_bf16x8(uint4 v) {
    union { uint4 u; bf16x8 b; } c; c.u = v; return c.b;
}

// =============================================================================
// Weight prep: gw,fw fp32 [K][128] -> Wt bf16 [256][K]  (cols 0..127 = gw,
// 128..255 = fw; cast + transpose, tiny)
// =============================================================================
__global__ void prep_w2(const float* __restrict__ gw, const float* __restrict__ fw,
                        unsigned short* __restrict__ Wt, int K)
{
    int t = blockIdx.x * 256 + threadIdx.x;
    if (t >= K * 256) return;
    int k = t >> 8, c = t & 255;
    float v = (c < 128) ? gw[(size_t)k * 128 + c] : fw[(size_t)k * 128 + (c - 128)];
    Wt[(size_t)c * K + k] = f2b(v);
}

// =============================================================================
// Fused dual GEMM v3: [h | y][M,256] = X[M,K] @ Wt[256,K]
// Tile 64(M) x 256(N), BK=32, 256 thr = 4 waves; wave w owns cols 64w..64w+63
// (4 col-tiles) x 64 rows (4 row-tiles) -> 16 MFMA/K-step.
// KEY CHANGE vs R5: B fragments are read DIRECTLY from global (Wt slab is
// 64-256 KB -> L2-resident; frag layout B[k=q*8+j][n] = one contiguous 16B
// load per lane), prefetched one K-step ahead into VGPRs. LDS stages A ONLY
// (5 KB/block) -> barrier drains 4x fewer bytes, no B bank conflicts, 1250
// blocks / ~3 resident per CU for cross-block latency hiding.
// Frag layouts (verified R3-R5): A[m=lane&15][k=q*8+j], B[k=q*8+j][n=lane&15],
// D col=lane&15, row=q*4+reg.
// =============================================================================
__global__ __launch_bounds__(256, 2) void gemm_dual(
    const float* __restrict__ X, const unsigned short* __restrict__ Wt,
    unsigned short* __restrict__ hb, float* __restrict__ yb, int M, int K,
    const float* __restrict__ fb, const float* __restrict__ fg,
    const float* __restrict__ fbeta, const float* __restrict__ gb)
{
    __shared__ __align__(16) char Asb[64 * 80];   // 64 rows x (32 bf16 + 16B pad)

    const int tid  = threadIdx.x;
    const int row0 = blockIdx.x * 64;
    const int w    = tid >> 6, lane = tid & 63;
    const int m    = lane & 15, q = lane >> 4;

    const int ra = tid >> 2, ka = (tid & 3) * 8;    // A stage: 8 floats/thread

    int arow = row0 + ra; if (arow >= M) arow = M - 1;

    f32x4 acc[4][4];
#pragma unroll
    for (int rt = 0; rt < 4; rt++)
#pragma unroll
        for (int ct = 0; ct < 4; ct++) acc[rt][ct] = (f32x4){0.f, 0.f, 0.f, 0.f};

    const int aw = ra * 80 + ka * 2;
    // B source: lane (m,q), wave w, col-tile ct -> Wt[(64w+ct*16+m)][ks+q*8]
    const unsigned short* Bbase = Wt + (size_t)(64 * w + m) * K + q * 8;

    // prologue: prefetch tile 0 (A + B)
    float4 pa0, pa1;
    uint4  pb[4];
    {
        const float* xr = X + (size_t)arow * K + ka;
        pa0 = *(const float4*)xr; pa1 = *(const float4*)(xr + 4);
#pragma unroll
        for (int ct = 0; ct < 4; ct++)
            pb[ct] = *(const uint4*)(Bbase + (size_t)(ct * 16) * K);
    }

    for (int ks = 0; ks < K; ks += 32) {
        __syncthreads();
        uint4 av;
        av.x = pack2(pa0.x, pa0.y); av.y = pack2(pa0.z, pa0.w);
        av.z = pack2(pa1.x, pa1.y); av.w = pack2(pa1.z, pa1.w);
        *(uint4*)(Asb + aw) = av;
        __syncthreads();

        uint4 bcur[4];
#pragma unroll
        for (int ct = 0; ct < 4; ct++) bcur[ct] = pb[ct];

        int kn = ks + 32;
        if (kn < K) {                      // prefetch tile kn (in flight during MFMA)
            const float* xr = X + (size_t)arow * K + kn + ka;
            pa0 = *(const float4*)xr; pa1 = *(const float4*)(xr + 4);
#pragma unroll
            for (int ct = 0; ct < 4; ct++)
                pb[ct] = *(const uint4*)(Bbase + (size_t)(ct * 16) * K + kn);
        }

        bf16x8 af[4];
#pragma unroll
        for (int rt = 0; rt < 4; rt++)
            af[rt] = *(const bf16x8*)(Asb + (rt * 16 + m) * 80 + q * 16);
#pragma unroll
        for (int rt = 0; rt < 4; rt++)
#pragma unroll
            for (int ct = 0; ct < 4; ct++)
                acc[rt][ct] = __builtin_amdgcn_mfma_f32_16x16x32_bf16(
                    af[rt], as_bf16x8(bcur[ct]), acc[rt][ct], 0, 0, 0);
    }

    // epilogue: D[row = row0+rt*16+q*4+r][gcol = 64w+ct*16+m]
    if (w < 2) {               // h half, bf16
#pragma unroll
        for (int ct = 0; ct < 4; ct++) {
            int col = 64 * w + ct * 16 + m;
#pragma unroll
            for (int rt = 0; rt < 4; rt++)
#pragma unroll
                for (int r = 0; r < 4; r++) {
                    int row = row0 + rt * 16 + q * 4 + r;
                    if (row < M) hb[(size_t)row * HD + col] = f2b(acc[rt][ct][r]);
                }
        }
    } else {                   // y half, fp32 with BN+relu+gb
        const float inv_bn = 1.0f / sqrtf(1.0f + BN_EPS);
#pragma unroll
        for (int ct = 0; ct < 4; ct++) {
            int col = 64 * (w - 2) + ct * 16 + m;
            float g  = fg[col] * inv_bn;
            float bb = fb[col];
            float bt = fbeta[col];
            float gv = gb[col];
#pragma unroll
            for (int rt = 0; rt < 4; rt++)
#pragma unroll
                for (int r = 0; r < 4; r++) {
                    int row = row0 + rt * 16 + q * 4 + r;
                    if (row < M) {
                        float y = (acc[rt][ct][r] + bb) * g + bt;
                        y = y > 0.f ? y : 0.f;       // feature_transform relu
                        yb[(size_t)row * HD + col] = y + gv;
                    }
                }
        }
    }
}

// ============================ attention logits ===============================
__global__ void al_kernel(const unsigned short* __restrict__ h,
                          const float* __restrict__ a_src, const float* __restrict__ a_dst,
                          float* __restrict__ als, float* __restrict__ ald, int N)
{
    int t = blockIdx.x * blockDim.x + threadIdx.x;
    if (t >= N * 4) return;
    int n = t >> 2, hd = t & 3;
    const unsigned short* hp = h + (size_t)n * HD + hd * 32;
    const float* as = a_src + hd * 32;
    const float* ad = a_dst + hd * 32;
    float s1 = 0.f, s2 = 0.f;
#pragma unroll
    for (int i = 0; i < 32; i += 8) {
        uint4 hv = *(const uint4*)(hp + i);
        unsigned int u[4] = {hv.x, hv.y, hv.z, hv.w};
#pragma unroll
        for (int p = 0; p < 4; p++) {
            float f0 = __uint_as_float(u[p] << 16);
            float f1 = __uint_as_float(u[p] & 0xffff0000u);
            s1 += f0 * as[i + 2 * p] + f1 * as[i + 2 * p + 1];
            s2 += f0 * ad[i + 2 * p] + f1 * ad[i + 2 * p + 1];
        }
    }
    als[t] = s1; ald[t] = s2;
}

// ============================ CSR build (once) ===============================
__global__ void hist_kernel(const int* __restrict__ ei, int E, int N, int* __restrict__ deg)
{
    int t = blockIdx.x * blockDim.x + threadIdx.x;
    if (t >= E + N) return;
    int d = (t < E) ? ei[E + t] : (t - E);
    atomicAdd(&deg[d], 1);
}

__global__ void scan1(const int* __restrict__ deg, int* __restrict__ rp,
                      int* __restrict__ bsum, int N)
{
    __shared__ int sh[256];
    int t = threadIdx.x;
    int i0 = blockIdx.x * 1024 + t * 4;
    int v[4];
#pragma unroll
    for (int j = 0; j < 4; j++) v[j] = (i0 + j < N) ? deg[i0 + j] : 0;
    int tot = v[0] + v[1] + v[2] + v[3];
    sh[t] = tot;
    __syncthreads();
    for (int off = 1; off < 256; off <<= 1) {
        int xv = (t >= off) ? sh[t - off] : 0;
        __syncthreads();
        sh[t] += xv;
        __syncthreads();
    }
    int run = sh[t] - tot;
    if (t == 255) bsum[blockIdx.x] = sh[255];
#pragma unroll
    for (int j = 0; j < 4; j++) {
        if (i0 + j < N) rp[i0 + j] = run;
        run += v[j];
    }
}

__global__ void scan2(int* __restrict__ bsum, int nb)
{
    if (threadIdx.x == 0 && blockIdx.x == 0) {
        int run = 0;
        for (int i = 0; i < nb; i++) { int v = bsum[i]; bsum[i] = run; run += v; }
    }
}

__global__ void scan3(int* __restrict__ rp, int* __restrict__ cur,
                      const int* __restrict__ bsum, int N, int Etot)
{
    int t = blockIdx.x * blockDim.x + threadIdx.x;
    if (t < N) {
        int v = rp[t] + bsum[t >> 10];
        rp[t] = v;
        cur[t] = v;
    } else if (t == N) {
        rp[N] = Etot;
    }
}

__global__ void scatter_kernel(const int* __restrict__ ei, int E, int N,
                               int* __restrict__ cur, int* __restrict__ col)
{
    int t = blockIdx.x * blockDim.x + threadIdx.x;
    if (t >= E + N) return;
    int s, d;
    if (t < E) { s = ei[t]; d = ei[E + t]; } else { s = t - E; d = t - E; }
    int p = atomicAdd(&cur[d], 1);
    col[p] = s;
}

// ============================ aggregation ====================================
// SINGLE-PASS per dst (no max-subtraction: logits ~N(0,sqrt2), exp fp32-safe;
// softmax value identical). One wave per dst; lane=(g=lane>>4 edge-slot,
// c=lane&15 channel-group, head=c>>2). 4 edges in flight; lane accumulates
// sum(exp*h[8ch]) and sum(exp); combine slots via shfl_xor(16|32).
__global__ __launch_bounds__(256) void agg_kernel(
    const unsigned short* __restrict__ h, const float* __restrict__ als,
    const float* __restrict__ ald, const int* __restrict__ rp,
    const int* __restrict__ col, float* __restrict__ xio, int N)
{
    int wid  = (blockIdx.x * blockDim.x + threadIdx.x) >> 6;
    int lane = threadIdx.x & 63;
    if (wid >= N) return;
    int beg = rp[wid], end = rp[wid + 1];

    int g = lane >> 4, c = lane & 15, hB = c >> 2;
    float ad_h = ald[wid * 4 + hB];
    float acc[8];
#pragma unroll
    for (int p = 0; p < 8; p++) acc[p] = 0.f;
    float wsum = 0.f;
    const unsigned short* hbase = h + c * 8;
    for (int j = beg + g; j < end; j += 4) {
        int s = col[j];
        float e = als[s * 4 + hB] + ad_h;
        e = e > 0.f ? e : NEG_SLOPE * e;
        float wgt = __expf(e);
        wsum += wgt;
        uint4 hv = *(const uint4*)(hbase + (size_t)s * HD);
        unsigned int uu[4] = {hv.x, hv.y, hv.z, hv.w};
#pragma unroll
        for (int p = 0; p < 4; p++) {
            acc[2 * p]     += wgt * __uint_as_float(uu[p] << 16);
            acc[2 * p + 1] += wgt * __uint_as_float(uu[p] & 0xffff0000u);
        }
    }
#pragma unroll
    for (int p = 0; p < 8; p++) {
        acc[p] += __shfl_xor(acc[p], 16);
        acc[p] += __shfl_xor(acc[p], 32);
    }
    wsum += __shfl_xor(wsum, 16);
    wsum += __shfl_xor(wsum, 32);
    if (g == 0) {
        float inv = 1.0f / wsum;
        float* xp = xio + (size_t)wid * HD + c * 8;
        float4 x0 = *(float4*)xp, x1 = *(float4*)(xp + 4);
        float o[8] = {acc[0] * inv + x0.x, acc[1] * inv + x0.y,
                      acc[2] * inv + x0.z, acc[3] * inv + x0.w,
                      acc[4] * inv + x1.x, acc[5] * inv + x1.y,
                      acc[6] * inv + x1.z, acc[7] * inv + x1.w};
#pragma unroll
        for (int p = 0; p < 8; p++) o[p] = o[p] > 0.f ? o[p] : 0.f;
        *(float4*)xp       = (float4){o[0], o[1], o[2], o[3]};
        *(float4*)(xp + 4) = (float4){o[4], o[5], o[6], o[7]};
    }
}

// ============================ classifier =====================================
__global__ __launch_bounds__(256) void cls_kernel(
    const float* __restrict__ x, const float* __restrict__ w,
    const float* __restrict__ b, float* __restrict__ out, int N)
{
    int wid  = (blockIdx.x * blockDim.x + threadIdx.x) >> 6;
    int lane = threadIdx.x & 63;
    if (wid >= N) return;
    float x0 = x[(size_t)wid * HD + lane];
    float x1 = x[(size_t)wid * HD + 64 + lane];
    float acc[10];
#pragma unroll
    for (int o = 0; o < 10; o++)
        acc[o] = x0 * w[lane * 10 + o] + x1 * w[(lane + 64) * 10 + o];
#pragma unroll
    for (int o = 0; o < 10; o++) {
        float v = acc[o];
#pragma unroll
        for (int off = 1; off < 64; off <<= 1) v += __shfl_xor(v, off);
        acc[o] = v;
    }
    float v = 0.f;
#pragma unroll
    for (int o = 0; o < 10; o++) if (lane == o) v = acc[o];
    if (lane < 10) out[(size_t)wid * 10 + lane] = v + b[lane];
}

// =============================================================================
extern "C" void kernel_launch(void* const* d_in, const int* in_sizes, int n_in,
                              void* d_out, int out_size, void* d_ws, size_t ws_size,
                              hipStream_t stream)
{
    const float* x0 = (const float*)d_in[0];
    const int*   ei = (const int*)d_in[1];
    const int N = in_sizes[0] / 512;
    const int E = in_sizes[1] / 2;
    const int Etot = E + N;

    const float *gw[3], *gas[3], *gad[3], *gbp[3], *fw[3], *fbp[3], *fgp[3], *fbt[3];
    for (int l = 0; l < 3; l++) {
        int b = 3 + 8 * l;
        gw[l]  = (const float*)d_in[b + 0];
        gas[l] = (const float*)d_in[b + 1];
        gad[l] = (const float*)d_in[b + 2];
        gbp[l] = (const float*)d_in[b + 3];
        fw[l]  = (const float*)d_in[b + 4];
        fbp[l] = (const float*)d_in[b + 5];
        fgp[l] = (const float*)d_in[b + 6];
        fbt[l] = (const float*)d_in[b + 7];
    }
    const float* cw = (const float*)d_in[27];
    const float* cb = (const float*)d_in[28];

    char* p = (char*)d_ws;
    auto carve = [&](size_t bytes) -> char* {
        char* r = p; p += (bytes + 255) & ~(size_t)255; return r;
    };
    float* xA   = (float*)carve((size_t)N * HD * 4);
    float* xB   = (float*)carve((size_t)N * HD * 4);
    unsigned short* hbuf = (unsigned short*)carve((size_t)N * HD * 2);   // bf16 h
    float* als  = (float*)carve((size_t)N * 4 * 4);
    float* ald  = (float*)carve((size_t)N * 4 * 4);
    int* rp   = (int*)carve((size_t)(N + 1) * 4);
    int* deg  = (int*)carve((size_t)N * 4);
    int* cur  = (int*)carve((size_t)N * 4);
    int* bsum = (int*)carve(4096);
    int* col  = (int*)carve((size_t)Etot * 4);
    unsigned short* wT[3];
    for (int l = 0; l < 3; l++) {
        int K = (l == 0) ? 512 : HD;
        wT[l] = (unsigned short*)carve((size_t)256 * K * 2);
    }

    // ---- weight cast+transpose+concat (tiny) ----
    for (int l = 0; l < 3; l++) {
        int K = (l == 0) ? 512 : HD;
        int nt = K * 256;
        prep_w2<<<(nt + 255) / 256, 256, 0, stream>>>(gw[l], fw[l], wT[l], K);
    }

    // ---- CSR by dst ----
    hipMemsetAsync(deg, 0, (size_t)N * 4, stream);
    hist_kernel<<<(Etot + 255) / 256, 256, 0, stream>>>(ei, E, N, deg);
    int nb = (N + 1023) / 1024;
    scan1<<<nb, 256, 0, stream>>>(deg, rp, bsum, N);
    scan2<<<1, 64, 0, stream>>>(bsum, nb);
    scan3<<<(N + 256) / 256, 256, 0, stream>>>(rp, cur, bsum, N, Etot);
    scatter_kernel<<<(Etot + 255) / 256, 256, 0, stream>>>(ei, E, N, cur, col);

    // ---- 3 message-passing layers ----
    for (int l = 0; l < 3; l++) {
        const float* xin = (l == 0) ? x0 : ((l == 1) ? xA : xB);
        float* xout = (l == 1) ? xB : xA;
        int K = (l == 0) ? 512 : HD;
        int mblocks = (N + 63) / 64;
        gemm_dual<<<mblocks, 256, 0, stream>>>(xin, wT[l], hbuf, xout, N, K,
                                               fbp[l], fgp[l], fbt[l], gbp[l]);
        al_kernel<<<(N * 4 + 255) / 256, 256, 0, stream>>>(hbuf, gas[l], gad[l], als, ald, N);
        agg_kernel<<<(N + 3) / 4, 256, 0, stream>>>(hbuf, als, ald, rp, col, xout, N);
    }

    // ---- classifier ----
    cls_kernel<<<(N + 3) / 4, 256, 0, stream>>>(xA, cw, cb, (float*)d_out, N);
}